// Round 5
// baseline (465.198 us; speedup 1.0000x reference)
//
#include <hip/hip_runtime.h>
#include <cstddef>

namespace {

constexpr int kB   = 8;
constexpr int kNQ  = 900;
constexpr int kD   = 256;
constexpr int kDFF = 1024;
constexpr int kLV  = 13294;

typedef short bf16x8 __attribute__((ext_vector_type(8)));
typedef float f32x4  __attribute__((ext_vector_type(4)));

__device__ inline unsigned short f2bf(float f) {
  union { float f; unsigned u; } v; v.f = f;
  return (unsigned short)((v.u + 0x7FFF + ((v.u >> 16) & 1)) >> 16);
}

__device__ inline bf16x8 pack_bf16x8(float4 a, float4 b) {
  bf16x8 r;
  r[0] = (short)f2bf(a.x); r[1] = (short)f2bf(a.y);
  r[2] = (short)f2bf(a.z); r[3] = (short)f2bf(a.w);
  r[4] = (short)f2bf(b.x); r[5] = (short)f2bf(b.y);
  r[6] = (short)f2bf(b.z); r[7] = (short)f2bf(b.w);
  return r;
}

// HW packed f32->bf16 (RNE): D.lo = cvt(a), D.hi = cvt(b)
__device__ inline unsigned cvt_pk_bf16(float a, float b) {
  unsigned r;
  asm("v_cvt_pk_bf16_f32 %0, %1, %2" : "=v"(r) : "v"(a), "v"(b));
  return r;
}

__device__ inline bf16x8 pack8_hw(float4 a, float4 b) {
  union { unsigned u[4]; bf16x8 v; } r;
  r.u[0] = cvt_pk_bf16(a.x, a.y);
  r.u[1] = cvt_pk_bf16(a.z, a.w);
  r.u[2] = cvt_pk_bf16(b.x, b.y);
  r.u[3] = cvt_pk_bf16(b.z, b.w);
  return r.v;
}

// ---------------------------------------------------------------------------
// K=256-specialized GEMM: C[M,N] = A[M,256] @ W[N,256]^T + bias (opt ReLU).
// Tile 128x128, 256 threads = 4 waves (2x2), 64x64 per wave.
// W tile staged ONCE to LDS (f32->bf16, XOR-swizzled, 64 KB); single barrier.
// A streamed global->fragment (2 x float4 + cvt_pk per frag); K fully
// unrolled; ZERO barriers in the K loop -> no vmcnt(0) drains, waves drift.
// ---------------------------------------------------------------------------
__global__ __launch_bounds__(256) void gemm_k256_kernel(
    const float* __restrict__ A, const float* __restrict__ W,
    const float* __restrict__ bias, float* __restrict__ C,
    int M, int N, int relu) {
  __shared__ short Ws[128 * 256];   // 64 KB

  const int t  = threadIdx.x;
  const int bm = blockIdx.y * 128;
  const int bn = blockIdx.x * 128;
  const int w  = t >> 6;
  const int l  = t & 63;
  const int wm = (w >> 1) * 64;
  const int wn = (w & 1) * 64;
  const int lr = l & 15;
  const int lc = l >> 4;

  // ---- stage W tile (128 rows x 256 k), f32 -> bf16, swizzled, once ----
#pragma unroll 4
  for (int i = 0; i < 32; ++i) {
    const int slot = i * 256 + t;       // 8192 float4 slots
    const int row  = slot >> 6;         // 64 float4 per row
    const int c4   = slot & 63;
    const float4 wv = *(const float4*)(W + (size_t)(bn + row) * 256 + c4 * 4);
    uint2 p;
    p.x = cvt_pk_bf16(wv.x, wv.y);
    p.y = cvt_pk_bf16(wv.z, wv.w);
    const int boff = (row * 512 + c4 * 8) ^ ((row & 7) << 4);
    *(uint2*)((char*)Ws + boff) = p;
  }
  __syncthreads();

  f32x4 acc[4][4];
#pragma unroll
  for (int m = 0; m < 4; ++m)
#pragma unroll
    for (int n = 0; n < 4; ++n) acc[m][n] = (f32x4){0.f, 0.f, 0.f, 0.f};

  // per-m A row pointers (rows constant across K)
  const float* apm[4];
#pragma unroll
  for (int m = 0; m < 4; ++m) {
    int row = bm + wm + m * 16 + lr;
    row = row < M ? row : M - 1;
    apm[m] = A + (size_t)row * 256;
  }

  // ---- K loop: 8 x (k-window of 32), no barriers ----
#pragma unroll
  for (int kk = 0; kk < 8; ++kk) {
    const int k = kk * 32 + lc * 8;
    bf16x8 af[4], bfr[4];
#pragma unroll
    for (int m = 0; m < 4; ++m) {
      const float4 a0 = *(const float4*)(apm[m] + k);
      const float4 a1 = *(const float4*)(apm[m] + k + 4);
      af[m] = pack8_hw(a0, a1);
    }
#pragma unroll
    for (int n = 0; n < 4; ++n) {
      const int row = wn + n * 16 + lr;
      const int boff = (row * 512 + k * 2) ^ ((row & 7) << 4);
      bfr[n] = *(const bf16x8*)((const char*)Ws + boff);
    }
#pragma unroll
    for (int m = 0; m < 4; ++m)
#pragma unroll
      for (int n = 0; n < 4; ++n)
        acc[m][n] = __builtin_amdgcn_mfma_f32_16x16x32_bf16(af[m], bfr[n], acc[m][n], 0, 0, 0);
  }

  // ---- epilogue: C/D layout col = l&15, row = (l>>4)*4 + j ----
  const int lr4 = (l >> 4) * 4;
  const int lcc = l & 15;
#pragma unroll
  for (int m = 0; m < 4; ++m) {
    const int rbase = bm + wm + m * 16 + lr4;
#pragma unroll
    for (int n = 0; n < 4; ++n) {
      const int col = bn + wn + n * 16 + lcc;
      const float bv = bias[col];
#pragma unroll
      for (int j = 0; j < 4; ++j) {
        const int r = rbase + j;
        if (r < M) {
          float v = acc[m][n][j] + bv;
          if (relu) v = fmaxf(v, 0.f);
          C[(size_t)r * N + col] = v;
        }
      }
    }
  }
}

// ---------------------------------------------------------------------------
// Generic GEMM (used for K=1024 FFN2): 128x128 tile, BK=64, reg-prefetch.
// ---------------------------------------------------------------------------
__global__ __launch_bounds__(256) void gemm_mfma_kernel(
    const float* __restrict__ A, const float* __restrict__ W,
    const float* __restrict__ bias, float* __restrict__ C,
    int M, int N, int K, int relu) {
  __shared__ short As[128 * 64];
  __shared__ short Bs[128 * 64];

  const int t  = threadIdx.x;
  const int bm = blockIdx.y * 128;
  const int bn = blockIdx.x * 128;
  const int w  = t >> 6;
  const int l  = t & 63;
  const int wm = (w >> 1) * 64;
  const int wn = (w & 1) * 64;

  f32x4 acc[4][4];
#pragma unroll
  for (int m = 0; m < 4; ++m)
#pragma unroll
    for (int n = 0; n < 4; ++n) acc[m][n] = (f32x4){0.f, 0.f, 0.f, 0.f};

  float4 pa[8], pw[8];
  auto load_tile = [&](int k0) {
#pragma unroll
    for (int i = 0; i < 8; ++i) {
      const int slot = i * 256 + t;
      const int row  = slot >> 4;
      const int c4   = slot & 15;
      const int ar   = bm + row;
      pa[i] = (ar < M) ? *(const float4*)(A + (size_t)ar * K + k0 + c4 * 4)
                       : make_float4(0.f, 0.f, 0.f, 0.f);
      pw[i] = *(const float4*)(W + (size_t)(bn + row) * K + k0 + c4 * 4);
    }
  };

  load_tile(0);

  for (int k0 = 0;;) {
#pragma unroll
    for (int i = 0; i < 8; ++i) {
      const int slot = i * 256 + t;
      const int row  = slot >> 4;
      const int c4   = slot & 15;
      const int boff = (row * 128 + c4 * 8) ^ ((row & 7) << 4);
      uint2 ap;
      ap.x = cvt_pk_bf16(pa[i].x, pa[i].y);
      ap.y = cvt_pk_bf16(pa[i].z, pa[i].w);
      *(uint2*)((char*)As + boff) = ap;
      uint2 wp;
      wp.x = cvt_pk_bf16(pw[i].x, pw[i].y);
      wp.y = cvt_pk_bf16(pw[i].z, pw[i].w);
      *(uint2*)((char*)Bs + boff) = wp;
    }
    __syncthreads();

    const int knext = k0 + 64;
    if (knext < K) load_tile(knext);

#pragma unroll
    for (int ks = 0; ks < 2; ++ks) {
      const int koff = (ks * 32 + (l >> 4) * 8) * 2;
      bf16x8 af[4], bfr[4];
#pragma unroll
      for (int m = 0; m < 4; ++m) {
        const int row = wm + m * 16 + (l & 15);
        af[m] = *(const bf16x8*)((const char*)As + ((row * 128 + koff) ^ ((row & 7) << 4)));
      }
#pragma unroll
      for (int n = 0; n < 4; ++n) {
        const int row = wn + n * 16 + (l & 15);
        bfr[n] = *(const bf16x8*)((const char*)Bs + ((row * 128 + koff) ^ ((row & 7) << 4)));
      }
#pragma unroll
      for (int m = 0; m < 4; ++m)
#pragma unroll
        for (int n = 0; n < 4; ++n)
          acc[m][n] = __builtin_amdgcn_mfma_f32_16x16x32_bf16(af[m], bfr[n], acc[m][n], 0, 0, 0);
    }

    k0 = knext;
    if (k0 >= K) break;
    __syncthreads();
  }

  const int lr4 = (l >> 4) * 4;
  const int lc  = l & 15;
#pragma unroll
  for (int m = 0; m < 4; ++m) {
    const int rbase = bm + wm + m * 16 + lr4;
#pragma unroll
    for (int n = 0; n < 4; ++n) {
      const int col = bn + wn + n * 16 + lc;
      const float bv = bias[col];
#pragma unroll
      for (int j = 0; j < 4; ++j) {
        const int r = rbase + j;
        if (r < M) {
          float v = acc[m][n][j] + bv;
          if (relu) v = fmaxf(v, 0.f);
          C[(size_t)r * N + col] = v;
        }
      }
    }
  }
}

// ---------------------------------------------------------------------------
// bf16 MFMA flash self-attention. qkv (B,NQ,768), head-dim 32, 8 heads.
// ---------------------------------------------------------------------------
__global__ __launch_bounds__(256) void self_attn_mfma_kernel(
    const float* __restrict__ qkv, float* __restrict__ out) {
  const int b = blockIdx.y >> 3;
  const int h = blockIdx.y & 7;
  const int t = threadIdx.x;
  const int w = t >> 6;
  const int l = t & 63;
  const int lr = l & 15;
  const int lc = l >> 4;

  __shared__ short Klds[64 * 40];
  __shared__ short Vt[32 * 68];
  __shared__ short Plds[4][16 * 68];

  const float scale = 0.17677669529663687f;
  const int qbase = blockIdx.x * 64 + w * 16;

  bf16x8 qf = {};
  {
    const int qr = qbase + lr;
    if (qr < kNQ) {
      const float* p = qkv + ((size_t)(b * kNQ + qr)) * 768 + h * 32 + lc * 8;
      float4 a = *(const float4*)p;
      float4 c = *(const float4*)(p + 4);
      a.x *= scale; a.y *= scale; a.z *= scale; a.w *= scale;
      c.x *= scale; c.y *= scale; c.z *= scale; c.w *= scale;
      qf = pack_bf16x8(a, c);
    }
  }

  f32x4 o0 = {0.f, 0.f, 0.f, 0.f}, o1 = {0.f, 0.f, 0.f, 0.f};
  const f32x4 zero4 = {0.f, 0.f, 0.f, 0.f};
  float mrun[4] = {-1e30f, -1e30f, -1e30f, -1e30f};
  float lrun[4] = {0.f, 0.f, 0.f, 0.f};

  for (int tb = 0; tb < kNQ; tb += 64) {
    {
      const int key = t & 63;
      const int c = t >> 6;
      const int kr = tb + key;
      float4 ka = make_float4(0.f, 0.f, 0.f, 0.f), kb2 = ka, va = ka, vb2 = ka;
      if (kr < kNQ) {
        const float* p = qkv + ((size_t)(b * kNQ + kr)) * 768 + h * 32 + c * 8;
        ka  = *(const float4*)(p + 256);
        kb2 = *(const float4*)(p + 260);
        va  = *(const float4*)(p + 512);
        vb2 = *(const float4*)(p + 516);
      }
      *(bf16x8*)&Klds[key * 40 + c * 8] = pack_bf16x8(ka, kb2);
      float vv[8] = {va.x, va.y, va.z, va.w, vb2.x, vb2.y, vb2.z, vb2.w};
#pragma unroll
      for (int i = 0; i < 8; ++i)
        Vt[(c * 8 + i) * 68 + key] = (short)f2bf(vv[i]);
    }
    __syncthreads();

    f32x4 s[4];
#pragma unroll
    for (int kt = 0; kt < 4; ++kt) {
      bf16x8 kf = *(const bf16x8*)&Klds[(kt * 16 + lr) * 40 + lc * 8];
      s[kt] = __builtin_amdgcn_mfma_f32_16x16x32_bf16(qf, kf, zero4, 0, 0, 0);
      if (tb + kt * 16 + lr >= kNQ) {
        s[kt][0] = -1e30f; s[kt][1] = -1e30f; s[kt][2] = -1e30f; s[kt][3] = -1e30f;
      }
    }

    float al[4];
#pragma unroll
    for (int j = 0; j < 4; ++j) {
      float mt = fmaxf(fmaxf(s[0][j], s[1][j]), fmaxf(s[2][j], s[3][j]));
#pragma unroll
      for (int mask = 1; mask < 16; mask <<= 1) mt = fmaxf(mt, __shfl_xor(mt, mask));
      const float mn = fmaxf(mrun[j], mt);
      al[j] = __expf(mrun[j] - mn);
      mrun[j] = mn;
    }
    float rs[4] = {0.f, 0.f, 0.f, 0.f};
#pragma unroll
    for (int kt = 0; kt < 4; ++kt)
#pragma unroll
      for (int j = 0; j < 4; ++j) {
        const float e = __expf(s[kt][j] - mrun[j]);
        s[kt][j] = e;
        rs[j] += e;
      }
#pragma unroll
    for (int j = 0; j < 4; ++j) {
#pragma unroll
      for (int mask = 1; mask < 16; mask <<= 1) rs[j] += __shfl_xor(rs[j], mask);
      lrun[j] = lrun[j] * al[j] + rs[j];
      o0[j] *= al[j];
      o1[j] *= al[j];
    }

    short* Pw = Plds[w];
#pragma unroll
    for (int kt = 0; kt < 4; ++kt)
#pragma unroll
      for (int j = 0; j < 4; ++j)
        Pw[(lc * 4 + j) * 68 + kt * 16 + lr] = (short)f2bf(s[kt][j]);

    bf16x8 pa0 = *(const bf16x8*)&Pw[lr * 68 + lc * 8];
    bf16x8 pa1 = *(const bf16x8*)&Pw[lr * 68 + 32 + lc * 8];
    bf16x8 v00 = *(const bf16x8*)&Vt[lr * 68 + lc * 8];
    bf16x8 v01 = *(const bf16x8*)&Vt[lr * 68 + 32 + lc * 8];
    bf16x8 v10 = *(const bf16x8*)&Vt[(16 + lr) * 68 + lc * 8];
    bf16x8 v11 = *(const bf16x8*)&Vt[(16 + lr) * 68 + 32 + lc * 8];

    o0 = __builtin_amdgcn_mfma_f32_16x16x32_bf16(pa0, v00, o0, 0, 0, 0);
    o0 = __builtin_amdgcn_mfma_f32_16x16x32_bf16(pa1, v01, o0, 0, 0, 0);
    o1 = __builtin_amdgcn_mfma_f32_16x16x32_bf16(pa0, v10, o1, 0, 0, 0);
    o1 = __builtin_amdgcn_mfma_f32_16x16x32_bf16(pa1, v11, o1, 0, 0, 0);
    __syncthreads();
  }

#pragma unroll
  for (int j = 0; j < 4; ++j) {
    const int q = qbase + lc * 4 + j;
    if (q < kNQ) {
      const float inv = 1.f / lrun[j];
      float* o = out + ((size_t)(b * kNQ + q)) * 256 + h * 32;
      o[lr]      = o0[j] * inv;
      o[16 + lr] = o1[j] * inv;
    }
  }
}

// ---------------------------------------------------------------------------
// out = LayerNorm(x + res) * g + b over rows of 256. One block per row.
// ---------------------------------------------------------------------------
__global__ __launch_bounds__(256) void ln_res_kernel(
    const float* __restrict__ x, const float* __restrict__ res,
    const float* __restrict__ g, const float* __restrict__ bta,
    float* __restrict__ out) {
  const int row = blockIdx.x;
  const int t = threadIdx.x;
  const size_t idx = (size_t)row * 256 + t;
  const float v = x[idx] + res[idx];
  float s = v, s2 = v * v;
#pragma unroll
  for (int mask = 1; mask < 64; mask <<= 1) {
    s  += __shfl_xor(s, mask);
    s2 += __shfl_xor(s2, mask);
  }
  __shared__ float ws[4], ws2[4];
  if ((t & 63) == 0) { ws[t >> 6] = s; ws2[t >> 6] = s2; }
  __syncthreads();
  const float S  = ws[0] + ws[1] + ws[2] + ws[3];
  const float S2 = ws2[0] + ws2[1] + ws2[2] + ws2[3];
  const float mean = S * (1.f / 256.f);
  const float var  = S2 * (1.f / 256.f) - mean * mean;
  const float rstd = rsqrtf(var + 1e-5f);
  out[idx] = (v - mean) * rstd * g[t] + bta[t];
}

// ---------------------------------------------------------------------------
// MS deformable attention. One block per (b,q).
// ---------------------------------------------------------------------------
__global__ __launch_bounds__(256) void deform_kernel(
    const float* __restrict__ value,   // (B, LV, 256)
    const float* __restrict__ offs,    // (B*NQ, 256)
    const float* __restrict__ awr,     // (B*NQ, 128)
    const float* __restrict__ refp,    // (B, NQ, 4, 2)
    float* __restrict__ out) {         // (B*NQ, 256)
  const int bq = blockIdx.x;
  const int b = bq / kNQ;
  const int t = threadIdx.x;

  __shared__ int   cidx[128][4];
  __shared__ float cw[128][4];

  if (t < 128) {
    const float a = awr[(size_t)bq * 128 + t];
    float mx = a;
#pragma unroll
    for (int mask = 1; mask < 16; mask <<= 1) mx = fmaxf(mx, __shfl_xor(mx, mask));
    const float e = __expf(a - mx);
    float se = e;
#pragma unroll
    for (int mask = 1; mask < 16; mask <<= 1) se += __shfl_xor(se, mask);
    const float aw = e / se;

    const int h = t >> 4, lp = t & 15, lvl = lp >> 2;
    const int HL[4] = {100, 50, 25, 13};
    const int WL[4] = {100, 50, 25, 13};
    const int ST[4] = {0, 10000, 12500, 13125};
    const int Hl = HL[lvl], Wl = WL[lvl], st = ST[lvl];
    const float rx = refp[((size_t)bq * 4 + lvl) * 2 + 0];
    const float ry = refp[((size_t)bq * 4 + lvl) * 2 + 1];
    const float ox = offs[(size_t)bq * 256 + h * 32 + lp * 2 + 0];
    const float oy = offs[(size_t)bq * 256 + h * 32 + lp * 2 + 1];
    const float x = rx * (float)Wl + ox - 0.5f;
    const float y = ry * (float)Hl + oy - 0.5f;
    const float x0f = floorf(x), y0f = floorf(y);
    const int x0 = (int)x0f, y0 = (int)y0f;
    const float lx = x - x0f, ly = y - y0f;
    const float wts[4] = {(1.f - lx) * (1.f - ly), lx * (1.f - ly),
                          (1.f - lx) * ly,         lx * ly};
    const int ys[4] = {y0, y0, y0 + 1, y0 + 1};
    const int xs[4] = {x0, x0 + 1, x0, x0 + 1};
#pragma unroll
    for (int c = 0; c < 4; ++c) {
      const int yy = ys[c], xx = xs[c];
      const bool valid = (yy >= 0) && (yy < Hl) && (xx >= 0) && (xx < Wl);
      const int yc = min(max(yy, 0), Hl - 1);
      const int xc = min(max(xx, 0), Wl - 1);
      cidx[t][c] = st + yc * Wl + xc;
      cw[t][c] = valid ? wts[c] * aw : 0.f;
    }
  }
  __syncthreads();

  const int h = t >> 5, d = t & 31;
  const float* vb = value + (size_t)b * kLV * 256 + h * 32 + d;
  float acc = 0.f;
#pragma unroll
  for (int s = 0; s < 16; ++s) {
    const int base = h * 16 + s;
#pragma unroll
    for (int c = 0; c < 4; ++c) {
      acc = fmaf(cw[base][c], vb[(size_t)cidx[base][c] * 256], acc);
    }
  }
  out[(size_t)bq * 256 + t] = acc;
}

}  // namespace

extern "C" void kernel_launch(void* const* d_in, const int* in_sizes, int n_in,
                              void* d_out, int out_size, void* d_ws, size_t ws_size,
                              hipStream_t stream) {
  const float* query  = (const float*)d_in[0];
  const float* refp   = (const float*)d_in[1];
  const float* memory = (const float*)d_in[2];
  const float* in_w  = (const float*)d_in[6];
  const float* in_b  = (const float*)d_in[7];
  const float* out_w = (const float*)d_in[8];
  const float* out_b = (const float*)d_in[9];
  const float* ln1g  = (const float*)d_in[10];
  const float* ln1b  = (const float*)d_in[11];
  const float* vp_w  = (const float*)d_in[12];
  const float* vp_b  = (const float*)d_in[13];
  const float* so_w  = (const float*)d_in[14];
  const float* so_b  = (const float*)d_in[15];
  const float* aw_w  = (const float*)d_in[16];
  const float* aw_b  = (const float*)d_in[17];
  const float* ca_w  = (const float*)d_in[18];
  const float* ca_b  = (const float*)d_in[19];
  const float* ln2g  = (const float*)d_in[20];
  const float* ln2b  = (const float*)d_in[21];
  const float* f1_w  = (const float*)d_in[22];
  const float* f1_b  = (const float*)d_in[23];
  const float* f2_w  = (const float*)d_in[24];
  const float* f2_b  = (const float*)d_in[25];
  const float* ln3g  = (const float*)d_in[26];
  const float* ln3b  = (const float*)d_in[27];
  float* out = (float*)d_out;

  const int MQ = kB * kNQ;   // 7200
  const int MV = kB * kLV;   // 106352

  float* ws = (float*)d_ws;
  size_t o = 0;
  float* qkv = ws;                              // 7200*768, overlaid with ffh
  float* ffh = ws;  o += (size_t)MQ * kDFF;
  float* sa   = ws + o;  o += (size_t)MQ * kD;
  float* q1   = ws + o;  o += (size_t)MQ * kD;
  float* val  = ws + o;  o += (size_t)MV * kD;
  float* offs = ws + o;  o += (size_t)MQ * kD;
  float* awr  = ws + o;  o += (size_t)MQ * 128;
  float* dfo  = ws + o;  o += (size_t)MQ * kD;
  float* q2   = ws + o;  o += (size_t)MQ * kD;
  float* tmp  = ws + o;  o += (size_t)MQ * kD;
  (void)ws_size; (void)in_sizes; (void)n_in; (void)out_size;

  const dim3 blk(256);
  auto g128 = [](int M, int N) { return dim3((unsigned)((N + 127) / 128), (unsigned)((M + 127) / 128)); };

  // 1. qkv = query @ in_proj^T + b
  gemm_k256_kernel<<<g128(MQ, 768), blk, 0, stream>>>(query, in_w, in_b, qkv, MQ, 768, 0);
  // 2. self-attention -> sa (MFMA flash)
  self_attn_mfma_kernel<<<dim3((kNQ + 63) / 64, kB * 8), blk, 0, stream>>>(qkv, sa);
  // 3. out-proj -> tmp
  gemm_k256_kernel<<<g128(MQ, kD), blk, 0, stream>>>(sa, out_w, out_b, tmp, MQ, kD, 0);
  // 4. q1 = LN(query + tmp)
  ln_res_kernel<<<MQ, blk, 0, stream>>>(query, tmp, ln1g, ln1b, q1);
  // 5. value = memory @ value_proj^T + b
  gemm_k256_kernel<<<g128(MV, kD), blk, 0, stream>>>(memory, vp_w, vp_b, val, MV, kD, 0);
  // 6. sampling offsets
  gemm_k256_kernel<<<g128(MQ, kD), blk, 0, stream>>>(q1, so_w, so_b, offs, MQ, kD, 0);
  // 7. attention weights (raw)
  gemm_k256_kernel<<<g128(MQ, 128), blk, 0, stream>>>(q1, aw_w, aw_b, awr, MQ, 128, 0);
  // 8. deformable attention -> dfo
  deform_kernel<<<MQ, blk, 0, stream>>>(val, offs, awr, refp, dfo);
  // 9. ca out-proj -> tmp
  gemm_k256_kernel<<<g128(MQ, kD), blk, 0, stream>>>(dfo, ca_w, ca_b, tmp, MQ, kD, 0);
  // 10. q2 = LN(q1 + tmp)
  ln_res_kernel<<<MQ, blk, 0, stream>>>(q1, tmp, ln2g, ln2b, q2);
  // 11. ffh = relu(q2 @ ffn_w1^T + b1)
  gemm_k256_kernel<<<g128(MQ, kDFF), blk, 0, stream>>>(q2, f1_w, f1_b, ffh, MQ, kDFF, 1);
  // 12. ffn out -> tmp (K=1024 -> generic kernel)
  gemm_mfma_kernel<<<g128(MQ, kD), blk, 0, stream>>>(ffh, f2_w, f2_b, tmp, MQ, kD, kDFF, 0);
  // 13. out = LN(q2 + tmp)
  ln_res_kernel<<<MQ, blk, 0, stream>>>(q2, tmp, ln3g, ln3b, out);
}

// Round 6
// 395.926 us; speedup vs baseline: 1.1750x; 1.1750x over previous
//
#include <hip/hip_runtime.h>
#include <cstddef>

namespace {

constexpr int kB   = 8;
constexpr int kNQ  = 900;
constexpr int kD   = 256;
constexpr int kDFF = 1024;
constexpr int kLV  = 13294;

typedef short bf16x8 __attribute__((ext_vector_type(8)));
typedef float f32x4  __attribute__((ext_vector_type(4)));

__device__ inline unsigned short f2bf(float f) {
  union { float f; unsigned u; } v; v.f = f;
  return (unsigned short)((v.u + 0x7FFF + ((v.u >> 16) & 1)) >> 16);
}

__device__ inline float bf2f(unsigned short u) {
  union { unsigned u; float f; } v; v.u = (unsigned)u << 16;
  return v.f;
}

__device__ inline bf16x8 pack_bf16x8(float4 a, float4 b) {
  bf16x8 r;
  r[0] = (short)f2bf(a.x); r[1] = (short)f2bf(a.y);
  r[2] = (short)f2bf(a.z); r[3] = (short)f2bf(a.w);
  r[4] = (short)f2bf(b.x); r[5] = (short)f2bf(b.y);
  r[6] = (short)f2bf(b.z); r[7] = (short)f2bf(b.w);
  return r;
}

// HW packed f32->bf16 (RNE)
__device__ inline unsigned cvt_pk_bf16(float a, float b) {
  unsigned r;
  asm("v_cvt_pk_bf16_f32 %0, %1, %2" : "=v"(r) : "v"(a), "v"(b));
  return r;
}

// ---------------------------------------------------------------------------
// Streaming f32 -> bf16 convert (8 floats / thread / iter).
// ---------------------------------------------------------------------------
__global__ __launch_bounds__(256) void f32_to_bf16_kernel(
    const float* __restrict__ in, unsigned* __restrict__ out, int n8) {
  int i = blockIdx.x * 256 + threadIdx.x;
  const int stride = gridDim.x * 256;
  for (; i < n8; i += stride) {
    const float4 a = ((const float4*)in)[(size_t)i * 2];
    const float4 b = ((const float4*)in)[(size_t)i * 2 + 1];
    uint4 r;
    r.x = cvt_pk_bf16(a.x, a.y);
    r.y = cvt_pk_bf16(a.z, a.w);
    r.z = cvt_pk_bf16(b.x, b.y);
    r.w = cvt_pk_bf16(b.z, b.w);
    ((uint4*)out)[i] = r;
  }
}

// ---------------------------------------------------------------------------
// Value GEMM: C_bf16[M,256] = A_bf16[M,256] @ W_f32[256,256]^T + bias.
// Tile 128x128, 4 waves (2x2), 64x64/wave. W staged once to swizzled LDS
// (single barrier). ALL 32 A-fragments (8 k-windows x 4 m) preloaded as
// direct global->register 16B loads BEFORE the MFMA loop: 32 outstanding
// vmem ops/wave hide HBM latency; compiler counts vmcnt down per window.
// Zero barriers in the K loop.
// ---------------------------------------------------------------------------
__global__ __launch_bounds__(256) void gemm_av_bf16_kernel(
    const unsigned short* __restrict__ A, const float* __restrict__ W,
    const float* __restrict__ bias, unsigned short* __restrict__ C,
    int M, int N) {
  __shared__ short Ws[128 * 256];   // 64 KB

  const int t  = threadIdx.x;
  const int bm = blockIdx.y * 128;
  const int bn = blockIdx.x * 128;
  const int w  = t >> 6;
  const int l  = t & 63;
  const int wm = (w >> 1) * 64;
  const int wn = (w & 1) * 64;
  const int lr = l & 15;
  const int lc = l >> 4;

  // ---- stage W tile (128 rows x 256 k), f32 -> bf16, swizzled, once ----
#pragma unroll 4
  for (int i = 0; i < 32; ++i) {
    const int slot = i * 256 + t;
    const int row  = slot >> 6;
    const int c4   = slot & 63;
    const float4 wv = *(const float4*)(W + (size_t)(bn + row) * 256 + c4 * 4);
    uint2 p;
    p.x = cvt_pk_bf16(wv.x, wv.y);
    p.y = cvt_pk_bf16(wv.z, wv.w);
    const int boff = (row * 512 + c4 * 8) ^ ((row & 7) << 4);
    *(uint2*)((char*)Ws + boff) = p;
  }
  __syncthreads();

  // ---- preload ALL A fragments (32 x 16B loads in flight) ----
  const unsigned short* apm[4];
#pragma unroll
  for (int m = 0; m < 4; ++m) {
    int row = bm + wm + m * 16 + lr;
    row = row < M ? row : M - 1;
    apm[m] = A + (size_t)row * 256 + lc * 8;
  }
  bf16x8 af[8][4];
#pragma unroll
  for (int kk = 0; kk < 8; ++kk)
#pragma unroll
    for (int m = 0; m < 4; ++m)
      af[kk][m] = *(const bf16x8*)(apm[m] + kk * 32);

  f32x4 acc[4][4];
#pragma unroll
  for (int m = 0; m < 4; ++m)
#pragma unroll
    for (int n = 0; n < 4; ++n) acc[m][n] = (f32x4){0.f, 0.f, 0.f, 0.f};

  // ---- K loop: 8 windows of 32, no barriers ----
#pragma unroll
  for (int kk = 0; kk < 8; ++kk) {
    const int k = kk * 32 + lc * 8;
    bf16x8 bfr[4];
#pragma unroll
    for (int n = 0; n < 4; ++n) {
      const int row = wn + n * 16 + lr;
      const int boff = (row * 512 + k * 2) ^ ((row & 7) << 4);
      bfr[n] = *(const bf16x8*)((const char*)Ws + boff);
    }
#pragma unroll
    for (int m = 0; m < 4; ++m)
#pragma unroll
      for (int n = 0; n < 4; ++n)
        acc[m][n] = __builtin_amdgcn_mfma_f32_16x16x32_bf16(af[kk][m], bfr[n], acc[m][n], 0, 0, 0);
  }

  // ---- epilogue: bf16 store; C/D layout col = l&15, row = (l>>4)*4 + j ----
  const int lr4 = (l >> 4) * 4;
  const int lcc = l & 15;
#pragma unroll
  for (int m = 0; m < 4; ++m) {
    const int rbase = bm + wm + m * 16 + lr4;
#pragma unroll
    for (int n = 0; n < 4; ++n) {
      const int col = bn + wn + n * 16 + lcc;
      const float bv = bias[col];
#pragma unroll
      for (int j = 0; j < 4; ++j) {
        const int r = rbase + j;
        if (r < M) C[(size_t)r * N + col] = f2bf(acc[m][n][j] + bv);
      }
    }
  }
}

// ---------------------------------------------------------------------------
// Generic GEMM: 128x128 tile, BK=64, reg-prefetch (r4 version).
// ---------------------------------------------------------------------------
__global__ __launch_bounds__(256) void gemm_mfma_kernel(
    const float* __restrict__ A, const float* __restrict__ W,
    const float* __restrict__ bias, float* __restrict__ C,
    int M, int N, int K, int relu) {
  __shared__ short As[128 * 64];
  __shared__ short Bs[128 * 64];

  const int t  = threadIdx.x;
  const int bm = blockIdx.y * 128;
  const int bn = blockIdx.x * 128;
  const int w  = t >> 6;
  const int l  = t & 63;
  const int wm = (w >> 1) * 64;
  const int wn = (w & 1) * 64;

  f32x4 acc[4][4];
#pragma unroll
  for (int m = 0; m < 4; ++m)
#pragma unroll
    for (int n = 0; n < 4; ++n) acc[m][n] = (f32x4){0.f, 0.f, 0.f, 0.f};

  float4 pa[8], pw[8];
  auto load_tile = [&](int k0) {
#pragma unroll
    for (int i = 0; i < 8; ++i) {
      const int slot = i * 256 + t;
      const int row  = slot >> 4;
      const int c4   = slot & 15;
      const int ar   = bm + row;
      pa[i] = (ar < M) ? *(const float4*)(A + (size_t)ar * K + k0 + c4 * 4)
                       : make_float4(0.f, 0.f, 0.f, 0.f);
      pw[i] = *(const float4*)(W + (size_t)(bn + row) * K + k0 + c4 * 4);
    }
  };

  load_tile(0);

  for (int k0 = 0;;) {
#pragma unroll
    for (int i = 0; i < 8; ++i) {
      const int slot = i * 256 + t;
      const int row  = slot >> 4;
      const int c4   = slot & 15;
      const int boff = (row * 128 + c4 * 8) ^ ((row & 7) << 4);
      uint2 ap;
      ap.x = cvt_pk_bf16(pa[i].x, pa[i].y);
      ap.y = cvt_pk_bf16(pa[i].z, pa[i].w);
      *(uint2*)((char*)As + boff) = ap;
      uint2 wp;
      wp.x = cvt_pk_bf16(pw[i].x, pw[i].y);
      wp.y = cvt_pk_bf16(pw[i].z, pw[i].w);
      *(uint2*)((char*)Bs + boff) = wp;
    }
    __syncthreads();

    const int knext = k0 + 64;
    if (knext < K) load_tile(knext);

#pragma unroll
    for (int ks = 0; ks < 2; ++ks) {
      const int koff = (ks * 32 + (l >> 4) * 8) * 2;
      bf16x8 af[4], bfr[4];
#pragma unroll
      for (int m = 0; m < 4; ++m) {
        const int row = wm + m * 16 + (l & 15);
        af[m] = *(const bf16x8*)((const char*)As + ((row * 128 + koff) ^ ((row & 7) << 4)));
      }
#pragma unroll
      for (int n = 0; n < 4; ++n) {
        const int row = wn + n * 16 + (l & 15);
        bfr[n] = *(const bf16x8*)((const char*)Bs + ((row * 128 + koff) ^ ((row & 7) << 4)));
      }
#pragma unroll
      for (int m = 0; m < 4; ++m)
#pragma unroll
        for (int n = 0; n < 4; ++n)
          acc[m][n] = __builtin_amdgcn_mfma_f32_16x16x32_bf16(af[m], bfr[n], acc[m][n], 0, 0, 0);
    }

    k0 = knext;
    if (k0 >= K) break;
    __syncthreads();
  }

  const int lr4 = (l >> 4) * 4;
  const int lc  = l & 15;
#pragma unroll
  for (int m = 0; m < 4; ++m) {
    const int rbase = bm + wm + m * 16 + lr4;
#pragma unroll
    for (int n = 0; n < 4; ++n) {
      const int col = bn + wn + n * 16 + lc;
      const float bv = bias[col];
#pragma unroll
      for (int j = 0; j < 4; ++j) {
        const int r = rbase + j;
        if (r < M) {
          float v = acc[m][n][j] + bv;
          if (relu) v = fmaxf(v, 0.f);
          C[(size_t)r * N + col] = v;
        }
      }
    }
  }
}

// ---------------------------------------------------------------------------
// bf16 MFMA flash self-attention. qkv (B,NQ,768), head-dim 32, 8 heads.
// ---------------------------------------------------------------------------
__global__ __launch_bounds__(256) void self_attn_mfma_kernel(
    const float* __restrict__ qkv, float* __restrict__ out) {
  const int b = blockIdx.y >> 3;
  const int h = blockIdx.y & 7;
  const int t = threadIdx.x;
  const int w = t >> 6;
  const int l = t & 63;
  const int lr = l & 15;
  const int lc = l >> 4;

  __shared__ short Klds[64 * 40];
  __shared__ short Vt[32 * 68];
  __shared__ short Plds[4][16 * 68];

  const float scale = 0.17677669529663687f;
  const int qbase = blockIdx.x * 64 + w * 16;

  bf16x8 qf = {};
  {
    const int qr = qbase + lr;
    if (qr < kNQ) {
      const float* p = qkv + ((size_t)(b * kNQ + qr)) * 768 + h * 32 + lc * 8;
      float4 a = *(const float4*)p;
      float4 c = *(const float4*)(p + 4);
      a.x *= scale; a.y *= scale; a.z *= scale; a.w *= scale;
      c.x *= scale; c.y *= scale; c.z *= scale; c.w *= scale;
      qf = pack_bf16x8(a, c);
    }
  }

  f32x4 o0 = {0.f, 0.f, 0.f, 0.f}, o1 = {0.f, 0.f, 0.f, 0.f};
  const f32x4 zero4 = {0.f, 0.f, 0.f, 0.f};
  float mrun[4] = {-1e30f, -1e30f, -1e30f, -1e30f};
  float lrun[4] = {0.f, 0.f, 0.f, 0.f};

  for (int tb = 0; tb < kNQ; tb += 64) {
    {
      const int key = t & 63;
      const int c = t >> 6;
      const int kr = tb + key;
      float4 ka = make_float4(0.f, 0.f, 0.f, 0.f), kb2 = ka, va = ka, vb2 = ka;
      if (kr < kNQ) {
        const float* p = qkv + ((size_t)(b * kNQ + kr)) * 768 + h * 32 + c * 8;
        ka  = *(const float4*)(p + 256);
        kb2 = *(const float4*)(p + 260);
        va  = *(const float4*)(p + 512);
        vb2 = *(const float4*)(p + 516);
      }
      *(bf16x8*)&Klds[key * 40 + c * 8] = pack_bf16x8(ka, kb2);
      float vv[8] = {va.x, va.y, va.z, va.w, vb2.x, vb2.y, vb2.z, vb2.w};
#pragma unroll
      for (int i = 0; i < 8; ++i)
        Vt[(c * 8 + i) * 68 + key] = (short)f2bf(vv[i]);
    }
    __syncthreads();

    f32x4 s[4];
#pragma unroll
    for (int kt = 0; kt < 4; ++kt) {
      bf16x8 kf = *(const bf16x8*)&Klds[(kt * 16 + lr) * 40 + lc * 8];
      s[kt] = __builtin_amdgcn_mfma_f32_16x16x32_bf16(qf, kf, zero4, 0, 0, 0);
      if (tb + kt * 16 + lr >= kNQ) {
        s[kt][0] = -1e30f; s[kt][1] = -1e30f; s[kt][2] = -1e30f; s[kt][3] = -1e30f;
      }
    }

    float al[4];
#pragma unroll
    for (int j = 0; j < 4; ++j) {
      float mt = fmaxf(fmaxf(s[0][j], s[1][j]), fmaxf(s[2][j], s[3][j]));
#pragma unroll
      for (int mask = 1; mask < 16; mask <<= 1) mt = fmaxf(mt, __shfl_xor(mt, mask));
      const float mn = fmaxf(mrun[j], mt);
      al[j] = __expf(mrun[j] - mn);
      mrun[j] = mn;
    }
    float rs[4] = {0.f, 0.f, 0.f, 0.f};
#pragma unroll
    for (int kt = 0; kt < 4; ++kt)
#pragma unroll
      for (int j = 0; j < 4; ++j) {
        const float e = __expf(s[kt][j] - mrun[j]);
        s[kt][j] = e;
        rs[j] += e;
      }
#pragma unroll
    for (int j = 0; j < 4; ++j) {
#pragma unroll
      for (int mask = 1; mask < 16; mask <<= 1) rs[j] += __shfl_xor(rs[j], mask);
      lrun[j] = lrun[j] * al[j] + rs[j];
      o0[j] *= al[j];
      o1[j] *= al[j];
    }

    short* Pw = Plds[w];
#pragma unroll
    for (int kt = 0; kt < 4; ++kt)
#pragma unroll
      for (int j = 0; j < 4; ++j)
        Pw[(lc * 4 + j) * 68 + kt * 16 + lr] = (short)f2bf(s[kt][j]);

    bf16x8 pa0 = *(const bf16x8*)&Pw[lr * 68 + lc * 8];
    bf16x8 pa1 = *(const bf16x8*)&Pw[lr * 68 + 32 + lc * 8];
    bf16x8 v00 = *(const bf16x8*)&Vt[lr * 68 + lc * 8];
    bf16x8 v01 = *(const bf16x8*)&Vt[lr * 68 + 32 + lc * 8];
    bf16x8 v10 = *(const bf16x8*)&Vt[(16 + lr) * 68 + lc * 8];
    bf16x8 v11 = *(const bf16x8*)&Vt[(16 + lr) * 68 + 32 + lc * 8];

    o0 = __builtin_amdgcn_mfma_f32_16x16x32_bf16(pa0, v00, o0, 0, 0, 0);
    o0 = __builtin_amdgcn_mfma_f32_16x16x32_bf16(pa1, v01, o0, 0, 0, 0);
    o1 = __builtin_amdgcn_mfma_f32_16x16x32_bf16(pa0, v10, o1, 0, 0, 0);
    o1 = __builtin_amdgcn_mfma_f32_16x16x32_bf16(pa1, v11, o1, 0, 0, 0);
    __syncthreads();
  }

#pragma unroll
  for (int j = 0; j < 4; ++j) {
    const int q = qbase + lc * 4 + j;
    if (q < kNQ) {
      const float inv = 1.f / lrun[j];
      float* o = out + ((size_t)(b * kNQ + q)) * 256 + h * 32;
      o[lr]      = o0[j] * inv;
      o[16 + lr] = o1[j] * inv;
    }
  }
}

// ---------------------------------------------------------------------------
// out = LayerNorm(x + res) * g + b over rows of 256. One block per row.
// ---------------------------------------------------------------------------
__global__ __launch_bounds__(256) void ln_res_kernel(
    const float* __restrict__ x, const float* __restrict__ res,
    const float* __restrict__ g, const float* __restrict__ bta,
    float* __restrict__ out) {
  const int row = blockIdx.x;
  const int t = threadIdx.x;
  const size_t idx = (size_t)row * 256 + t;
  const float v = x[idx] + res[idx];
  float s = v, s2 = v * v;
#pragma unroll
  for (int mask = 1; mask < 64; mask <<= 1) {
    s  += __shfl_xor(s, mask);
    s2 += __shfl_xor(s2, mask);
  }
  __shared__ float ws[4], ws2[4];
  if ((t & 63) == 0) { ws[t >> 6] = s; ws2[t >> 6] = s2; }
  __syncthreads();
  const float S  = ws[0] + ws[1] + ws[2] + ws[3];
  const float S2 = ws2[0] + ws2[1] + ws2[2] + ws2[3];
  const float mean = S * (1.f / 256.f);
  const float var  = S2 * (1.f / 256.f) - mean * mean;
  const float rstd = rsqrtf(var + 1e-5f);
  out[idx] = (v - mean) * rstd * g[t] + bta[t];
}

// ---------------------------------------------------------------------------
// MS deformable attention. One block per (b,q). value is bf16.
// ---------------------------------------------------------------------------
__global__ __launch_bounds__(256) void deform_kernel(
    const unsigned short* __restrict__ value,   // (B, LV, 256) bf16
    const float* __restrict__ offs,    // (B*NQ, 256)
    const float* __restrict__ awr,     // (B*NQ, 128)
    const float* __restrict__ refp,    // (B, NQ, 4, 2)
    float* __restrict__ out) {         // (B*NQ, 256)
  const int bq = blockIdx.x;
  const int b = bq / kNQ;
  const int t = threadIdx.x;

  __shared__ int   cidx[128][4];
  __shared__ float cw[128][4];

  if (t < 128) {
    const float a = awr[(size_t)bq * 128 + t];
    float mx = a;
#pragma unroll
    for (int mask = 1; mask < 16; mask <<= 1) mx = fmaxf(mx, __shfl_xor(mx, mask));
    const float e = __expf(a - mx);
    float se = e;
#pragma unroll
    for (int mask = 1; mask < 16; mask <<= 1) se += __shfl_xor(se, mask);
    const float aw = e / se;

    const int h = t >> 4, lp = t & 15, lvl = lp >> 2;
    const int HL[4] = {100, 50, 25, 13};
    const int WL[4] = {100, 50, 25, 13};
    const int ST[4] = {0, 10000, 12500, 13125};
    const int Hl = HL[lvl], Wl = WL[lvl], st = ST[lvl];
    const float rx = refp[((size_t)bq * 4 + lvl) * 2 + 0];
    const float ry = refp[((size_t)bq * 4 + lvl) * 2 + 1];
    const float ox = offs[(size_t)bq * 256 + h * 32 + lp * 2 + 0];
    const float oy = offs[(size_t)bq * 256 + h * 32 + lp * 2 + 1];
    const float x = rx * (float)Wl + ox - 0.5f;
    const float y = ry * (float)Hl + oy - 0.5f;
    const float x0f = floorf(x), y0f = floorf(y);
    const int x0 = (int)x0f, y0 = (int)y0f;
    const float lx = x - x0f, ly = y - y0f;
    const float wts[4] = {(1.f - lx) * (1.f - ly), lx * (1.f - ly),
                          (1.f - lx) * ly,         lx * ly};
    const int ys[4] = {y0, y0, y0 + 1, y0 + 1};
    const int xs[4] = {x0, x0 + 1, x0, x0 + 1};
#pragma unroll
    for (int c = 0; c < 4; ++c) {
      const int yy = ys[c], xx = xs[c];
      const bool valid = (yy >= 0) && (yy < Hl) && (xx >= 0) && (xx < Wl);
      const int yc = min(max(yy, 0), Hl - 1);
      const int xc = min(max(xx, 0), Wl - 1);
      cidx[t][c] = st + yc * Wl + xc;
      cw[t][c] = valid ? wts[c] * aw : 0.f;
    }
  }
  __syncthreads();

  const int h = t >> 5, d = t & 31;
  const unsigned short* vb = value + (size_t)b * kLV * 256 + h * 32 + d;
  float acc = 0.f;
#pragma unroll
  for (int s = 0; s < 16; ++s) {
    const int base = h * 16 + s;
#pragma unroll
    for (int c = 0; c < 4; ++c) {
      acc = fmaf(cw[base][c], bf2f(vb[(size_t)cidx[base][c] * 256]), acc);
    }
  }
  out[(size_t)bq * 256 + t] = acc;
}

}  // namespace

extern "C" void kernel_launch(void* const* d_in, const int* in_sizes, int n_in,
                              void* d_out, int out_size, void* d_ws, size_t ws_size,
                              hipStream_t stream) {
  const float* query  = (const float*)d_in[0];
  const float* refp   = (const float*)d_in[1];
  const float* memory = (const float*)d_in[2];
  const float* in_w  = (const float*)d_in[6];
  const float* in_b  = (const float*)d_in[7];
  const float* out_w = (const float*)d_in[8];
  const float* out_b = (const float*)d_in[9];
  const float* ln1g  = (const float*)d_in[10];
  const float* ln1b  = (const float*)d_in[11];
  const float* vp_w  = (const float*)d_in[12];
  const float* vp_b  = (const float*)d_in[13];
  const float* so_w  = (const float*)d_in[14];
  const float* so_b  = (const float*)d_in[15];
  const float* aw_w  = (const float*)d_in[16];
  const float* aw_b  = (const float*)d_in[17];
  const float* ca_w  = (const float*)d_in[18];
  const float* ca_b  = (const float*)d_in[19];
  const float* ln2g  = (const float*)d_in[20];
  const float* ln2b  = (const float*)d_in[21];
  const float* f1_w  = (const float*)d_in[22];
  const float* f1_b  = (const float*)d_in[23];
  const float* f2_w  = (const float*)d_in[24];
  const float* f2_b  = (const float*)d_in[25];
  const float* ln3g  = (const float*)d_in[26];
  const float* ln3b  = (const float*)d_in[27];
  float* out = (float*)d_out;

  const int MQ = kB * kNQ;   // 7200
  const int MV = kB * kLV;   // 106352

  float* ws = (float*)d_ws;
  size_t o = 0;
  float* qkv = ws;                              // 7200*768, overlaid with ffh
  float* ffh = ws;  o += (size_t)MQ * kDFF;
  float* sa   = ws + o;  o += (size_t)MQ * kD;
  float* q1   = ws + o;  o += (size_t)MQ * kD;
  float* valr = ws + o;  o += (size_t)MV * kD;  // region: val_bf | m_bf (both bf16)
  float* offs = ws + o;  o += (size_t)MQ * kD;
  float* awr  = ws + o;  o += (size_t)MQ * 128;
  float* dfo  = ws + o;  o += (size_t)MQ * kD;
  float* q2   = ws + o;  o += (size_t)MQ * kD;
  float* tmp  = ws + o;  o += (size_t)MQ * kD;
  (void)ws_size; (void)in_sizes; (void)n_in; (void)out_size;

  unsigned short* val_bf = (unsigned short*)valr;                        // MV*256 bf16
  unsigned short* m_bf   = (unsigned short*)(valr + (size_t)MV * kD / 2); // MV*256 bf16

  const dim3 blk(256);
  auto g128 = [](int M, int N) { return dim3((unsigned)((N + 127) / 128), (unsigned)((M + 127) / 128)); };

  // 0. memory -> bf16
  f32_to_bf16_kernel<<<2048, blk, 0, stream>>>(memory, (unsigned*)m_bf, MV * kD / 8);
  // 1. qkv = query @ in_proj^T + b
  gemm_mfma_kernel<<<g128(MQ, 768), blk, 0, stream>>>(query, in_w, in_b, qkv, MQ, 768, kD, 0);
  // 2. self-attention -> sa (MFMA flash)
  self_attn_mfma_kernel<<<dim3((kNQ + 63) / 64, kB * 8), blk, 0, stream>>>(qkv, sa);
  // 3. out-proj -> tmp
  gemm_mfma_kernel<<<g128(MQ, kD), blk, 0, stream>>>(sa, out_w, out_b, tmp, MQ, kD, kD, 0);
  // 4. q1 = LN(query + tmp)
  ln_res_kernel<<<MQ, blk, 0, stream>>>(query, tmp, ln1g, ln1b, q1);
  // 5. value = m_bf @ value_proj^T + b  (bf16 in, bf16 out, full A-preload)
  gemm_av_bf16_kernel<<<g128(MV, kD), blk, 0, stream>>>(m_bf, vp_w, vp_b, val_bf, MV, kD);
  // 6. sampling offsets
  gemm_mfma_kernel<<<g128(MQ, kD), blk, 0, stream>>>(q1, so_w, so_b, offs, MQ, kD, kD, 0);
  // 7. attention weights (raw)
  gemm_mfma_kernel<<<g128(MQ, 128), blk, 0, stream>>>(q1, aw_w, aw_b, awr, MQ, 128, kD, 0);
  // 8. deformable attention -> dfo
  deform_kernel<<<MQ, blk, 0, stream>>>(val_bf, offs, awr, refp, dfo);
  // 9. ca out-proj -> tmp
  gemm_mfma_kernel<<<g128(MQ, kD), blk, 0, stream>>>(dfo, ca_w, ca_b, tmp, MQ, kD, kD, 0);
  // 10. q2 = LN(q1 + tmp)
  ln_res_kernel<<<MQ, blk, 0, stream>>>(q1, tmp, ln2g, ln2b, q2);
  // 11. ffh = relu(q2 @ ffn_w1^T + b1)
  gemm_mfma_kernel<<<g128(MQ, kDFF), blk, 0, stream>>>(q2, f1_w, f1_b, ffh, MQ, kDFF, kD, 1);
  // 12. ffn out -> tmp (K=1024)
  gemm_mfma_kernel<<<g128(MQ, kD), blk, 0, stream>>>(ffh, f2_w, f2_b, tmp, MQ, kD, kDFF, 0);
  // 13. out = LN(q2 + tmp)
  ln_res_kernel<<<MQ, blk, 0, stream>>>(q2, tmp, ln3g, ln3b, out);
}